// Round 7
// baseline (288.505 us; speedup 1.0000x reference)
//
#include <hip/hip_runtime.h>
#include <hip/hip_bf16.h>

// FourierAttention: x[4,2048,1024] f32; single-head attention over d_model=1024.
// Algebra: out = P·(x·Wvo^T) + (Wo·bv + bo), Wvo = Wo·Wv  (softmax rows sum to 1).
//
// Round-7:
//  * gemm256_bt: SAME 4-phase schedule/LDS/swizzle as R6 (best measured), but
//    16 waves (1024 thr) instead of 8 -> 4 waves/SIMD for latency hiding
//    (R6 counters: MfmaUtil 30 / Occ 18 / HBM 17 -> stall-exposed at 2 w/SIMD).
//    Each wave owns 64x64 spanning all 4 quadrants (32 rows + 32 cols per
//    half) so every phase has full MFMA work. Stage = 1 gload_lds/thread ->
//    ledger rescales exactly: WAITV(4) per phase, prologue 6 stages WAITV(4).
//    Same publish proof: each half retired by a WAITV *before* a barrier that
//    precedes its readers (1-phase-early publication, phase-for-phase = R6).
//  * Launch trims: 1 merged weight-convert kernel (Wq,Wk,Wo), bias_vo+cat
//    fused. 13 -> 10 launches.
//  * gemm128_bt (PV, VWo) unchanged from R6 (passed, <42.5us).
// LDS swizzle: 16B granule ^= (row&7), pre-swizzled global source + linear
// global_load_lds dest; same XOR on ds_read (involution; 0 bank conflicts).
// y-fastest bijective XCD decode (R6: FETCH 41->24.8MB, MfmaUtil 21.6->30).

#define TILE 128
#define BK 32
#define BUFE (TILE * BK)

typedef __attribute__((ext_vector_type(8))) short bf16x8;
typedef __attribute__((ext_vector_type(4))) float f32x4;

// ==================== old 128x128 core (kept for the tiny Wvo GEMM) ==========
__device__ __forceinline__ void stage_tiles(
    const __hip_bfloat16* __restrict__ Ab, const __hip_bfloat16* __restrict__ Bb,
    __hip_bfloat16* As, __hip_bfloat16* Bs,
    long rowBase, long colBase, int K, int k0, int tid)
{
  #pragma unroll
  for (int p = 0; p < 2; ++p) {
    int seg = tid + p * 256;
    int r   = seg >> 2;
    int cq  = seg & 3;
    const __hip_bfloat16* ga = Ab + (rowBase + r) * (long)K + k0 + cq * 8;
    __builtin_amdgcn_global_load_lds(
        (const __attribute__((address_space(1))) void*)ga,
        (__attribute__((address_space(3))) void*)(As + seg * 8), 16, 0, 0);
    const __hip_bfloat16* gb = Bb + (colBase + r) * (long)K + k0 + cq * 8;
    __builtin_amdgcn_global_load_lds(
        (const __attribute__((address_space(1))) void*)gb,
        (__attribute__((address_space(3))) void*)(Bs + seg * 8), 16, 0, 0);
  }
}

__device__ __forceinline__ void gemm_core(
    const __hip_bfloat16* __restrict__ Ab, const __hip_bfloat16* __restrict__ Bb,
    __hip_bfloat16* As, __hip_bfloat16* Bs,
    long rowBase, long colBase, int K, int tid, int wr, int wc, int lr, int q,
    f32x4 acc[4][4])
{
  stage_tiles(Ab, Bb, As, Bs, rowBase, colBase, K, 0, tid);
  int buf = 0;
  for (int k0 = 0; k0 < K; k0 += BK, buf ^= 1) {
    __syncthreads();
    if (k0 + BK < K)
      stage_tiles(Ab, Bb, As + (buf ^ 1) * BUFE, Bs + (buf ^ 1) * BUFE,
                  rowBase, colBase, K, k0 + BK, tid);
    const __hip_bfloat16* Ac = As + buf * BUFE;
    const __hip_bfloat16* Bc = Bs + buf * BUFE;
    bf16x8 af[4], bfr[4];
    #pragma unroll
    for (int mi = 0; mi < 4; ++mi)
      af[mi] = *(const bf16x8*)(Ac + (wr + mi * 16 + lr) * BK + q * 8);
    #pragma unroll
    for (int ni = 0; ni < 4; ++ni)
      bfr[ni] = *(const bf16x8*)(Bc + (wc + ni * 16 + lr) * BK + q * 8);
    #pragma unroll
    for (int mi = 0; mi < 4; ++mi)
      #pragma unroll
      for (int ni = 0; ni < 4; ++ni)
        acc[mi][ni] = __builtin_amdgcn_mfma_f32_16x16x32_bf16(
            af[mi], bfr[ni], acc[mi][ni], 0, 0, 0);
  }
}

__global__ __launch_bounds__(256) void gemm_bt(
    const __hip_bfloat16* __restrict__ A,
    const __hip_bfloat16* __restrict__ B,
    void* __restrict__ Cv,
    const float* __restrict__ bias,
    int K, int ldC,
    long sA, long sB, long sC,
    float scale, int mode)
{
  const long z = blockIdx.z;
  __shared__ __hip_bfloat16 As[2 * BUFE];
  __shared__ __hip_bfloat16 Bs[2 * BUFE];
  const int tid  = threadIdx.x;
  const int lane = tid & 63;
  const int wid  = tid >> 6;
  const int wr   = (wid >> 1) * 64;
  const int wc   = (wid & 1) * 64;
  const int lr   = lane & 15;
  const int q    = lane >> 4;
  const long rowBase = (long)blockIdx.x * TILE;
  const long colBase = (long)blockIdx.y * TILE;

  f32x4 acc[4][4] = {};
  gemm_core(A + z * sA, B + z * sB, As, Bs, rowBase, colBase, K,
            tid, wr, wc, lr, q, acc);

  #pragma unroll
  for (int ni = 0; ni < 4; ++ni) {
    long col = colBase + wc + ni * 16 + lr;
    float bv = bias ? bias[col] : 0.0f;
    #pragma unroll
    for (int mi = 0; mi < 4; ++mi) {
      #pragma unroll
      for (int i = 0; i < 4; ++i) {
        long row = rowBase + wr + mi * 16 + q * 4 + i;
        float v = acc[mi][ni][i] * scale + bv;
        if (mode == 0)
          ((__hip_bfloat16*)Cv)[z * sC + row * (long)ldC + col] = __float2bfloat16(v);
        else
          ((float*)Cv)[z * sC + row * (long)ldC + col] = v;
      }
    }
  }
}

// ==================== shared helpers for the big-tile cores ==================
// 512-thread staging (gemm128): 2 loads/thread.
__device__ __forceinline__ void stage_half(
    const __hip_bfloat16* __restrict__ g, __hip_bfloat16* lds,
    long rowBase, int ld, int k0, int tid)
{
  #pragma unroll
  for (int j = 0; j < 2; ++j) {
    int idx = tid + j * 512;               // 0..1023 -> 128 rows x 8 granules
    int r   = idx >> 3;
    int cg  = (idx & 7) ^ (r & 7);         // pre-swizzled source granule
    const __hip_bfloat16* src = g + (rowBase + r) * (long)ld + k0 + cg * 8;
    __builtin_amdgcn_global_load_lds(
        (const __attribute__((address_space(1))) void*)src,
        (__attribute__((address_space(3))) void*)(lds + idx * 8), 16, 0, 0);
  }
}

// 1024-thread staging (gemm256 w16): 1 load/thread.
__device__ __forceinline__ void stage_half_1k(
    const __hip_bfloat16* __restrict__ g, __hip_bfloat16* lds,
    long rowBase, int ld, int k0, int tid)
{
  int r  = tid >> 3;                       // 0..127
  int cg = (tid & 7) ^ (r & 7);            // pre-swizzled source granule
  const __hip_bfloat16* src = g + (rowBase + r) * (long)ld + k0 + cg * 8;
  __builtin_amdgcn_global_load_lds(
      (const __attribute__((address_space(1))) void*)src,
      (__attribute__((address_space(3))) void*)(lds + tid * 8), 16, 0, 0);
}

__device__ __forceinline__ bf16x8 frag256(const __hip_bfloat16* half_, int row, int off)
{
  const char* p = (const char*)half_ + row * 128 + (off ^ ((row & 7) << 4));
  return *(const bf16x8*)p;
}

#define WAITV(N) asm volatile("s_waitcnt vmcnt(" #N ")" ::: "memory")
#define BAR __builtin_amdgcn_s_barrier()

// y-fastest bijective XCD remap: chunk of consecutive lin shares few panels.
__device__ __forceinline__ void xcd_decode(int NX, int NY, int NZ,
                                           int& bx, int& by, long& z)
{
  const int nwg = NX * NY * NZ;
  int lin = (int)blockIdx.x + NX * ((int)blockIdx.y + NY * (int)blockIdx.z);
  int xcd = lin & 7, off = lin >> 3;
  int q8 = nwg >> 3, r8 = nwg & 7;
  lin = ((xcd < r8) ? xcd * (q8 + 1) : r8 * (q8 + 1) + (xcd - r8) * q8) + off;
  by = lin % NY;               // y fastest within a chunk
  bx = (lin / NY) % NX;
  z  = lin / (NY * NX);
}

// ==================== 256x256 4-phase core, 16 waves =========================
// C[M,N] = A[M,K]·B[N,K]^T * scale + bias; mode 0 = bf16 store, 2 = f32.
// Wave (wid) owns 64 rows x 64 cols: 32 rows in each A-half (wrr=(wid>>2)*32)
// and 32 cols in each B-half (wcc=(wid&3)*32) -> acc[4][4], m<2 = A-half0,
// n<2 = B-half0. Phases p0..p3 compute quadrants (0,0),(0,1),(1,1),(1,0).
// Ledger (1 load/stage/wave): WAITV(4) per phase; each half retired exactly
// one phase before its read, published by that phase's closing BAR.
__global__ __launch_bounds__(1024, 1) void gemm256_bt(
    const __hip_bfloat16* __restrict__ A,
    const __hip_bfloat16* __restrict__ B,
    void* __restrict__ Cv,
    const float* __restrict__ bias,
    int K, int ldA, int ldB, int ldC,
    long sA_, long sB_, long sC_,
    float scale, int mode)
{
  __shared__ __hip_bfloat16 L[2][2][2][128 * 64];   // [buf][mat][half]

  const int tid  = threadIdx.x;
  const int lane = tid & 63;
  const int wid  = tid >> 6;          // 0..15
  const int wrr  = (wid >> 2) * 32;   // row base within an A-half
  const int wcc  = (wid & 3) * 32;    // col base within a B-half
  const int lr   = lane & 15;
  const int q    = lane >> 4;
  const int q16  = q * 16;

  int bx, by; long z;
  xcd_decode(gridDim.x, gridDim.y, gridDim.z, bx, by, z);

  const long rowBase = (long)bx * 256;
  const long colBase = (long)by * 256;
  const __hip_bfloat16* Ab = A + z * sA_;
  const __hip_bfloat16* Bb = B + z * sB_;

  f32x4 acc[4][4] = {};
  bf16x8 a[4], bA[4], bB[4];
  const int KT = K >> 6;

  // ---- prologue: 6 stages (6 loads/wave), publish A0[0],B0[0] ----
  {
    const int kk1 = (KT > 1 ? 1 : 0) * 64;
    stage_half_1k(Ab, &L[0][0][0][0], rowBase,       ldA, 0,   tid);  // A0[0]
    stage_half_1k(Bb, &L[0][1][0][0], colBase,       ldB, 0,   tid);  // B0[0]
    stage_half_1k(Bb, &L[0][1][1][0], colBase + 128, ldB, 0,   tid);  // B1[0]
    stage_half_1k(Ab, &L[0][0][1][0], rowBase + 128, ldA, 0,   tid);  // A1[0]
    stage_half_1k(Ab, &L[1][0][0][0], rowBase,       ldA, kk1, tid);  // A0[1]
    stage_half_1k(Bb, &L[1][1][0][0], colBase,       ldB, kk1, tid);  // B0[1]
    WAITV(4);   // retire A0[0], B0[0]
    BAR;
  }

  for (int kt = 0; kt < KT; ++kt) {
    const int cur = kt & 1, nxt = cur ^ 1;
    const int t1 = kt + 1 < KT ? kt + 1 : KT - 1;
    const int t2 = kt + 2 < KT ? kt + 2 : KT - 1;
    const int k1 = t1 << 6, k2 = t2 << 6;

    // ---- p0 : quadrant (Ah0, Bh0) ----
    stage_half_1k(Bb, &L[nxt][1][1][0], colBase + 128, ldB, k1, tid); // B1[t+1]
    WAITV(4);
    #pragma unroll
    for (int ks = 0; ks < 2; ++ks)
      #pragma unroll
      for (int mi = 0; mi < 2; ++mi)
        a[ks * 2 + mi] =
            frag256(&L[cur][0][0][0], wrr + mi * 16 + lr, ks * 64 + q16);
    #pragma unroll
    for (int ks = 0; ks < 2; ++ks)
      #pragma unroll
      for (int ni = 0; ni < 2; ++ni)
        bA[ks * 2 + ni] =
            frag256(&L[cur][1][0][0], wcc + ni * 16 + lr, ks * 64 + q16);
    BAR;
    __builtin_amdgcn_s_setprio(1);
    #pragma unroll
    for (int ks = 0; ks < 2; ++ks)
      #pragma unroll
      for (int mi = 0; mi < 2; ++mi)
        #pragma unroll
        for (int ni = 0; ni < 2; ++ni)
          acc[mi][ni] = __builtin_amdgcn_mfma_f32_16x16x32_bf16(
              a[ks * 2 + mi], bA[ks * 2 + ni], acc[mi][ni], 0, 0, 0);
    __builtin_amdgcn_s_setprio(0);
    // ---- p1 : quadrant (Ah0, Bh1) ----
    stage_half_1k(Ab, &L[nxt][0][1][0], rowBase + 128, ldA, k1, tid); // A1[t+1]
    WAITV(4);
    #pragma unroll
    for (int ks = 0; ks < 2; ++ks)
      #pragma unroll
      for (int ni = 0; ni < 2; ++ni)
        bB[ks * 2 + ni] =
            frag256(&L[cur][1][1][0], wcc + ni * 16 + lr, ks * 64 + q16);
    BAR;
    __builtin_amdgcn_s_setprio(1);
    #pragma unroll
    for (int ks = 0; ks < 2; ++ks)
      #pragma unroll
      for (int mi = 0; mi < 2; ++mi)
        #pragma unroll
        for (int ni = 0; ni < 2; ++ni)
          acc[mi][2 + ni] = __builtin_amdgcn_mfma_f32_16x16x32_bf16(
              a[ks * 2 + mi], bB[ks * 2 + ni], acc[mi][2 + ni], 0, 0, 0);
    __builtin_amdgcn_s_setprio(0);
    // ---- p2 : quadrant (Ah1, Bh1) ----
    stage_half_1k(Ab, &L[cur][0][0][0], rowBase, ldA, k2, tid);       // A0[t+2]
    WAITV(4);
    #pragma unroll
    for (int ks = 0; ks < 2; ++ks)
      #pragma unroll
      for (int mi = 0; mi < 2; ++mi)
        a[ks * 2 + mi] =
            frag256(&L[cur][0][1][0], wrr + mi * 16 + lr, ks * 64 + q16);
    BAR;
    __builtin_amdgcn_s_setprio(1);
    #pragma unroll
    for (int ks = 0; ks < 2; ++ks)
      #pragma unroll
      for (int mi = 0; mi < 2; ++mi)
        #pragma unroll
        for (int ni = 0; ni < 2; ++ni)
          acc[2 + mi][2 + ni] = __builtin_amdgcn_mfma_f32_16x16x32_bf16(
              a[ks * 2 + mi], bB[ks * 2 + ni], acc[2 + mi][2 + ni], 0, 0, 0);
    __builtin_amdgcn_s_setprio(0);
    // ---- p3 : quadrant (Ah1, Bh0) — no reads (a holds Ah1, bA held) ----
    stage_half_1k(Bb, &L[cur][1][0][0], colBase, ldB, k2, tid);       // B0[t+2]
    WAITV(4);
    BAR;
    __builtin_amdgcn_s_setprio(1);
    #pragma unroll
    for (int ks = 0; ks < 2; ++ks)
      #pragma unroll
      for (int mi = 0; mi < 2; ++mi)
        #pragma unroll
        for (int ni = 0; ni < 2; ++ni)
          acc[2 + mi][ni] = __builtin_amdgcn_mfma_f32_16x16x32_bf16(
              a[ks * 2 + mi], bA[ks * 2 + ni], acc[2 + mi][ni], 0, 0, 0);
    __builtin_amdgcn_s_setprio(0);
  }
  WAITV(0);   // drain redundant tail stages

  // ---- epilogue ----
  const long cz = z * sC_;
  #pragma unroll
  for (int n = 0; n < 4; ++n) {
    long col = colBase + (n >> 1) * 128 + wcc + (n & 1) * 16 + lr;
    float bv = bias ? bias[col] : 0.0f;
    #pragma unroll
    for (int m = 0; m < 4; ++m) {
      long row0 = rowBase + (m >> 1) * 128 + wrr + (m & 1) * 16 + q * 4;
      f32x4 v = acc[m][n];
      #pragma unroll
      for (int i = 0; i < 4; ++i) {
        float val = v[i] * scale + bv;
        if (mode == 0)
          ((__hip_bfloat16*)Cv)[cz + (row0 + i) * (long)ldC + col] =
              __float2bfloat16(val);
        else
          ((float*)Cv)[cz + (row0 + i) * (long)ldC + col] = val;
      }
    }
  }
}

// ==================== 128x256 2-phase triple-buffered core (R6, passing) =====
__global__ __launch_bounds__(512, 2) void gemm128_bt(
    const __hip_bfloat16* __restrict__ A,
    const __hip_bfloat16* __restrict__ B,
    void* __restrict__ Cv,
    const float* __restrict__ bias,
    int K, int ldA, int ldB, int ldC,
    long sA_, long sB_, long sC_,
    float scale, int mode)
{
  __shared__ __hip_bfloat16 L[3][3][128 * 64];   // [buf][region]

  const int tid  = threadIdx.x;
  const int lane = tid & 63;
  const int wid  = tid >> 6;
  const int wr   = (wid >> 2) * 64;
  const int wc   = (wid & 3) * 32;
  const int lr   = lane & 15;
  const int q    = lane >> 4;
  const int q16  = q * 16;

  int bx, by; long z;
  xcd_decode(gridDim.x, gridDim.y, gridDim.z, bx, by, z);

  const long rowBase = (long)bx * 128;
  const long colBase = (long)by * 256;
  const __hip_bfloat16* Ab = A + z * sA_;
  const __hip_bfloat16* Bb = B + z * sB_;

  f32x4 acc[4][4] = {};
  bf16x8 a[8], bA[4], bB[4];
  const int KT = K >> 6;

  // ---- prologue: tiles 0,1 (12 loads); publish A[0],B0[0] ----
  {
    const int kk1 = (KT > 1 ? 1 : 0) * 64;
    stage_half(Ab, &L[0][0][0], rowBase,       ldA, 0,   tid);  // A[0]
    stage_half(Bb, &L[0][1][0], colBase,       ldB, 0,   tid);  // B0[0]
    stage_half(Bb, &L[0][2][0], colBase + 128, ldB, 0,   tid);  // B1[0]
    stage_half(Ab, &L[1][0][0], rowBase,       ldA, kk1, tid);  // A[1]
    stage_half(Bb, &L[1][1][0], colBase,       ldB, kk1, tid);  // B0[1]
    stage_half(Bb, &L[1][2][0], colBase + 128, ldB, kk1, tid);  // B1[1]
    WAITV(8);   // retire A[0],B0[0]
    BAR;
  }

  int cur = 0, nx2 = 2;
  for (int t = 0; t < KT; ++t) {
    const int kc = ((t + 2 < KT) ? (t + 2) : (KT - 1)) << 6;
    // ---- ph0 ----
    stage_half(Ab, &L[nx2][0][0], rowBase,       ldA, kc, tid);  // A[t+2]
    stage_half(Bb, &L[nx2][1][0], colBase,       ldB, kc, tid);  // B0[t+2]
    WAITV(10);                                   // publish B1[t]
    #pragma unroll
    for (int ks = 0; ks < 2; ++ks)
      #pragma unroll
      for (int mi = 0; mi < 4; ++mi)
        a[ks * 4 + mi] = frag256(&L[cur][0][0], wr + mi * 16 + lr, ks * 64 + q16);
    #pragma unroll
    for (int ks = 0; ks < 2; ++ks)
      #pragma unroll
      for (int ni = 0; ni < 2; ++ni)
        bA[ks * 2 + ni] = frag256(&L[cur][1][0], wc + ni * 16 + lr, ks * 64 + q16);
    BAR;
    __builtin_amdgcn_s_setprio(1);
    #pragma unroll
    for (int ks = 0; ks < 2; ++ks)
      #pragma unroll
      for (int mi = 0; mi < 4; ++mi)
        #pragma unroll
        for (int ni = 0; ni < 2; ++ni)
          acc[mi][ni] = __builtin_amdgcn_mfma_f32_16x16x32_bf16(
              a[ks * 4 + mi], bA[ks * 2 + ni], acc[mi][ni], 0, 0, 0);
    __builtin_amdgcn_s_setprio(0);
    // ---- ph1 ----
    stage_half(Bb, &L[nx2][2][0], colBase + 128, ldB, kc, tid);  // B1[t+2]
    WAITV(8);                                    // publish A[t+1],B0[t+1]
    #pragma unroll
    for (int ks = 0; ks < 2; ++ks)
      #pragma unroll
      for (int ni = 0; ni < 2; ++ni)
        bB[ks * 2 + ni] = frag256(&L[cur][2][0], wc + ni * 16 + lr, ks * 64 + q16);
    BAR;
    __builtin_amdgcn_s_setprio(1);
    #pragma unroll
    for (int ks = 0; ks < 2; ++ks)
      #pragma unroll
      for (int mi = 0; mi < 4; ++mi)
        #pragma unroll
        for (int ni = 0; ni < 2; ++ni)
          acc[mi][2 + ni] = __builtin_amdgcn_mfma_f32_16x16x32_bf16(
              a[ks * 4 + mi], bB[ks * 2 + ni], acc[mi][2 + ni], 0, 0, 0);
    __builtin_amdgcn_s_setprio(0);
    cur = (cur == 2) ? 0 : cur + 1;
    nx2 = (nx2 == 2) ? 0 : nx2 + 1;
  }
  WAITV(0);

  // ---- epilogue ----
  const long cz = z * sC_;
  #pragma unroll
  for (int n = 0; n < 4; ++n) {
    long col = colBase + (n >> 1) * 128 + wc + (n & 1) * 16 + lr;
    float bv = bias ? bias[col] : 0.0f;
    #pragma unroll
    for (int m = 0; m < 4; ++m) {
      long row0 = rowBase + wr + m * 16 + q * 4;
      f32x4 v = acc[m][n];
      #pragma unroll
      for (int i = 0; i < 4; ++i) {
        float val = v[i] * scale + bv;
        if (mode == 0)
          ((__hip_bfloat16*)Cv)[cz + (row0 + i) * (long)ldC + col] =
              __float2bfloat16(val);
        else
          ((float*)Cv)[cz + (row0 + i) * (long)ldC + col] = val;
      }
    }
  }
}

// ==================== small helpers ==========================================
__global__ __launch_bounds__(256) void cvt_f32_bf16(
    const float* __restrict__ in, __hip_bfloat16* __restrict__ out)
{
  long i = ((long)blockIdx.x * 256 + threadIdx.x) * 8;
  float4 a = *(const float4*)(in + i);
  float4 b = *(const float4*)(in + i + 4);
  bf16x8 o;
  o[0] = __builtin_bit_cast(short, __float2bfloat16(a.x));
  o[1] = __builtin_bit_cast(short, __float2bfloat16(a.y));
  o[2] = __builtin_bit_cast(short, __float2bfloat16(a.z));
  o[3] = __builtin_bit_cast(short, __float2bfloat16(a.w));
  o[4] = __builtin_bit_cast(short, __float2bfloat16(b.x));
  o[5] = __builtin_bit_cast(short, __float2bfloat16(b.y));
  o[6] = __builtin_bit_cast(short, __float2bfloat16(b.z));
  o[7] = __builtin_bit_cast(short, __float2bfloat16(b.w));
  *(bf16x8*)(out + i) = o;
}

// Merged straight converts: Wq, Wk, Wo (512 blocks each).
__global__ __launch_bounds__(256) void cvt_w3_f32_bf16(
    const float* __restrict__ Wq, const float* __restrict__ Wk,
    const float* __restrict__ Wo,
    __hip_bfloat16* __restrict__ oQ, __hip_bfloat16* __restrict__ oK,
    __hip_bfloat16* __restrict__ oO)
{
  int blk = blockIdx.x;
  const float* in; __hip_bfloat16* out;
  if (blk < 512)        { in = Wq; out = oQ; }
  else if (blk < 1024)  { in = Wk; out = oK; blk -= 512; }
  else                  { in = Wo; out = oO; blk -= 1024; }
  long i = ((long)blk * 256 + threadIdx.x) * 8;
  float4 a = *(const float4*)(in + i);
  float4 b = *(const float4*)(in + i + 4);
  bf16x8 o;
  o[0] = __builtin_bit_cast(short, __float2bfloat16(a.x));
  o[1] = __builtin_bit_cast(short, __float2bfloat16(a.y));
  o[2] = __builtin_bit_cast(short, __float2bfloat16(a.z));
  o[3] = __builtin_bit_cast(short, __float2bfloat16(a.w));
  o[4] = __builtin_bit_cast(short, __float2bfloat16(b.x));
  o[5] = __builtin_bit_cast(short, __float2bfloat16(b.y));
  o[6] = __builtin_bit_cast(short, __float2bfloat16(b.z));
  o[7] = __builtin_bit_cast(short, __float2bfloat16(b.w));
  *(bf16x8*)(out + i) = o;
}

__global__ __launch_bounds__(256) void cvt_t_f32_bf16(
    const float* __restrict__ in, __hip_bfloat16* __restrict__ out)
{
  __shared__ __hip_bfloat16 t[64][65];
  const int tid = threadIdx.x;
  const long rb = (long)blockIdx.y * 64;
  const long cb = (long)blockIdx.x * 64;
  const int r0 = tid >> 4;
  const int c0 = (tid & 15) * 4;
  #pragma unroll
  for (int p = 0; p < 4; ++p) {
    int r = r0 + p * 16;
    float4 v = *(const float4*)(in + (rb + r) * 1024 + cb + c0);
    t[c0 + 0][r] = __float2bfloat16(v.x);
    t[c0 + 1][r] = __float2bfloat16(v.y);
    t[c0 + 2][r] = __float2bfloat16(v.z);
    t[c0 + 3][r] = __float2bfloat16(v.w);
  }
  __syncthreads();
  #pragma unroll
  for (int p = 0; p < 4; ++p) {
    int r = r0 + p * 16;
    __hip_bfloat16* o = out + (cb + r) * 1024 + rb + c0;
    o[0] = t[r][c0 + 0]; o[1] = t[r][c0 + 1];
    o[2] = t[r][c0 + 2]; o[3] = t[r][c0 + 3];
  }
}

// Fused: blocks 0..255 -> bfinal = Wo·bv + bo ; blocks 256..263 -> bqk = bq|bk.
__global__ __launch_bounds__(256) void bias_fuse(
    const float* __restrict__ Wo, const float* __restrict__ bv,
    const float* __restrict__ bo, const float* __restrict__ bq,
    const float* __restrict__ bk, float* __restrict__ bfinal,
    float* __restrict__ bqk)
{
  int blk = blockIdx.x;
  if (blk < 256) {
    int e = blk * 4 + (threadIdx.x >> 6);
    int lane = threadIdx.x & 63;
    const float* row = Wo + (long)e * 1024;
    float s = 0.0f;
    #pragma unroll
    for (int p = 0; p < 4; ++p) {
      float4 w = *(const float4*)(row + p * 256 + lane * 4);
      float4 b = *(const float4*)(bv + p * 256 + lane * 4);
      s += w.x * b.x + w.y * b.y + w.z * b.z + w.w * b.w;
    }
    #pragma unroll
    for (int o = 32; o; o >>= 1) s += __shfl_xor(s, o);
    if (lane == 0) bfinal[e] = s + bo[e];
  } else {
    int i = (blk - 256) * 256 + threadIdx.x;
    bqk[i] = (i < 1024) ? bq[i] : bk[i - 1024];
  }
}

__global__ __launch_bounds__(256) void softmax_rows(__hip_bfloat16* __restrict__ P)
{
  const int tid  = threadIdx.x;
  const int lane = tid & 63;
  const int wid  = tid >> 6;
  __hip_bfloat16* p = P + (long)blockIdx.x * 2048 + tid * 8;

  bf16x8 v = *(const bf16x8*)p;
  float x[8];
  #pragma unroll
  for (int i = 0; i < 8; ++i)
    x[i] = __uint_as_float(((unsigned)(unsigned short)v[i]) << 16);

  float m = x[0];
  #pragma unroll
  for (int i = 1; i < 8; ++i) m = fmaxf(m, x[i]);
  #pragma unroll
  for (int o = 32; o; o >>= 1) m = fmaxf(m, __shfl_xor(m, o));

  __shared__ float rmax[4], rsum[4];
  if (lane == 0) rmax[wid] = m;
  __syncthreads();
  m = fmaxf(fmaxf(rmax[0], rmax[1]), fmaxf(rmax[2], rmax[3]));

  float e[8], s = 0.0f;
  #pragma unroll
  for (int i = 0; i < 8; ++i) { e[i] = __expf(x[i] - m); s += e[i]; }
  #pragma unroll
  for (int o = 32; o; o >>= 1) s += __shfl_xor(s, o);
  if (lane == 0) rsum[wid] = s;
  __syncthreads();
  s = (rsum[0] + rsum[1]) + (rsum[2] + rsum[3]);

  float inv = 1.0f / s;
  bf16x8 ov;
  #pragma unroll
  for (int i = 0; i < 8; ++i) {
    __hip_bfloat16 h = __float2bfloat16(e[i] * inv);
    ov[i] = __builtin_bit_cast(short, h);
  }
  *(bf16x8*)p = ov;
}

extern "C" void kernel_launch(void* const* d_in, const int* in_sizes, int n_in,
                              void* d_out, int out_size, void* d_ws, size_t ws_size,
                              hipStream_t stream) {
  const float* x  = (const float*)d_in[0];
  const float* Wq = (const float*)d_in[1];
  const float* bq = (const float*)d_in[2];
  const float* Wk = (const float*)d_in[3];
  const float* bk = (const float*)d_in[4];
  const float* Wv = (const float*)d_in[5];
  const float* bv = (const float*)d_in[6];
  const float* Wo = (const float*)d_in[7];
  const float* bo = (const float*)d_in[8];
  float* out = (float*)d_out;

  const long B = 4, S = 2048, D = 1024;
  char* ws = (char*)d_ws;
  __hip_bfloat16* xb   = (__hip_bfloat16*)ws; ws += B * S * D * 2;     // 16 MiB
  __hip_bfloat16* Wqkb = (__hip_bfloat16*)ws; ws += 2 * D * D * 2;     //  4 MiB (Wq|Wk rows)
  __hip_bfloat16* Wob  = (__hip_bfloat16*)ws; ws += D * D * 2;         //  2 MiB
  __hip_bfloat16* QK   = (__hip_bfloat16*)ws; ws += (B * S) * (2 * D) * 2; // 32 MiB [8192][2048]
  __hip_bfloat16* VWot = (__hip_bfloat16*)ws; ws += B * D * S * 2;     // 16 MiB [B][D][S]
  __hip_bfloat16* P    = (__hip_bfloat16*)ws; ws += B * S * S * 2;     // 32 MiB
  // Aliases (dead-region reuse):
  __hip_bfloat16* Wvtb   = QK;                   // Wv^T bf16, dead before QK write
  __hip_bfloat16* Wvo    = P;                    // Wvo bf16, dead before P write
  float*          bfinal = (float*)Wob;          // after Wvo GEMM reads Wob
  float*          bqk    = (float*)Wob + 1024;   // concat(bq,bk), same region

  dim3 blk(256);
  dim3 blk5(512);
  dim3 blkX(1024);
  // converts (3 launches)
  cvt_f32_bf16<<<dim3(4096), blk, 0, stream>>>(x, xb);
  cvt_w3_f32_bf16<<<dim3(1536), blk, 0, stream>>>(Wq, Wk, Wo,
                                                  Wqkb, Wqkb + D * D, Wob);
  cvt_t_f32_bf16<<<dim3(16, 16), blk, 0, stream>>>(Wv, Wvtb);

  // Wvo = Wo · Wv (via Wv^T), 128² core (tiny) -> P region head
  gemm_bt<<<dim3(8, 8, 1), blk, 0, stream>>>(Wob, Wvtb, Wvo,
                                             nullptr, 1024, 1024, 0, 0, 0, 1.0f, 0);
  // bfinal = Wo·bv + bo ; bqk = bq|bk  (overwrites Wob region — after Wvo GEMM)
  bias_fuse<<<dim3(264), blk, 0, stream>>>(Wo, bv, bo, bq, bk, bfinal, bqk);

  // QK = xb · Wqkb^T + (bq|bk):  M=8192, N=2048, K=1024  -> [8192][2048]
  gemm256_bt<<<dim3(32, 8, 1), blkX, 0, stream>>>(
      xb, Wqkb, QK, bqk, 1024, 1024, 1024, 2048, 0, 0, 0, 1.0f, 0);
  // VWo^T = Wvo · xb^T (batched): M=1024, N=2048, K=1024 -> [B][D][S]
  gemm128_bt<<<dim3(8, 8, 4), blk5, 0, stream>>>(
      Wvo, xb, VWot, nullptr, 1024, 1024, 1024, 2048, 0, S * D, D * S, 1.0f, 0);
  // scores: P = Q·K^T * 0.125 (batched): M=N=2048, K=1024
  gemm256_bt<<<dim3(8, 8, 4), blkX, 0, stream>>>(
      QK, QK + 1024, P, nullptr, 1024, 2048, 2048, 2048,
      S * 2048, S * 2048, S * S, 0.125f, 0);
  // softmax over each of 4*2048 rows
  softmax_rows<<<dim3(8192), blk, 0, stream>>>(P);
  // out = P · VWot^T + bfinal (f32): M=2048, N=1024, K=2048 (batched)
  gemm128_bt<<<dim3(16, 4, 4), blk5, 0, stream>>>(
      P, VWot, out, bfinal, 2048, 2048, 2048, 1024,
      S * S, D * S, S * D, 1.0f, 2);
}

// Round 8
// 260.154 us; speedup vs baseline: 1.1090x; 1.1090x over previous
//
#include <hip/hip_runtime.h>
#include <hip/hip_bf16.h>

// FourierAttention: x[4,2048,1024] f32; single-head attention over d_model=1024.
// Algebra: out = P·(x·Wvo^T) + (Wo·bv + bo), Wvo = Wo·Wv  (softmax rows sum to 1).
//
// Round-8:
//  * gemm256_bt: exact R6 version (8 waves / 512 thr, 4-phase, WAITV(8)) —
//    best measured (42.9us QK, MfmaUtil 30). R7's 16-wave variant regressed
//    (47.5us, MfmaUtil 26): extra waves are barrier-coupled AND the 4x4 wave
//    decomposition raises LDS read traffic 192->256 KB/K-tile. Reverted.
//  * Wvo = Wo·Wv parallelized: K-split z=4 chunks of 256 on the PROVEN
//    gemm128 core (grid 8x4x4=128 blocks; z-strides express the K-offset),
//    f32 partials + tiny reduce->bf16. Replaces the serial 64-block 128² GEMM
//    (1 block/CU, nothing hides its barrier drains).
//  * Merged weight convert + fused bias kernels (R7 trims kept).
// LDS swizzle: 16B granule ^= (row&7), pre-swizzled global source + linear
// global_load_lds dest; same XOR on ds_read (involution; 0 bank conflicts).
// y-fastest bijective XCD decode (R6: FETCH 41->24.8MB, MfmaUtil 21.6->30).

typedef __attribute__((ext_vector_type(8))) short bf16x8;
typedef __attribute__((ext_vector_type(4))) short bf16x4;
typedef __attribute__((ext_vector_type(4))) float f32x4;

// ==================== shared helpers for the big-tile cores ==================
// 512-thread staging: 2 loads/thread, 128 rows x 64 cols bf16.
__device__ __forceinline__ void stage_half(
    const __hip_bfloat16* __restrict__ g, __hip_bfloat16* lds,
    long rowBase, int ld, int k0, int tid)
{
  #pragma unroll
  for (int j = 0; j < 2; ++j) {
    int idx = tid + j * 512;               // 0..1023 -> 128 rows x 8 granules
    int r   = idx >> 3;
    int cg  = (idx & 7) ^ (r & 7);         // pre-swizzled source granule
    const __hip_bfloat16* src = g + (rowBase + r) * (long)ld + k0 + cg * 8;
    __builtin_amdgcn_global_load_lds(
        (const __attribute__((address_space(1))) void*)src,
        (__attribute__((address_space(3))) void*)(lds + idx * 8), 16, 0, 0);
  }
}

__device__ __forceinline__ bf16x8 frag256(const __hip_bfloat16* half_, int row, int off)
{
  const char* p = (const char*)half_ + row * 128 + (off ^ ((row & 7) << 4));
  return *(const bf16x8*)p;
}

#define WAITV(N) asm volatile("s_waitcnt vmcnt(" #N ")" ::: "memory")
#define BAR __builtin_amdgcn_s_barrier()

// y-fastest bijective XCD remap: chunk of consecutive lin shares few panels.
__device__ __forceinline__ void xcd_decode(int NX, int NY, int NZ,
                                           int& bx, int& by, long& z)
{
  const int nwg = NX * NY * NZ;
  int lin = (int)blockIdx.x + NX * ((int)blockIdx.y + NY * (int)blockIdx.z);
  int xcd = lin & 7, off = lin >> 3;
  int q8 = nwg >> 3, r8 = nwg & 7;
  lin = ((xcd < r8) ? xcd * (q8 + 1) : r8 * (q8 + 1) + (xcd - r8) * q8) + off;
  by = lin % NY;               // y fastest within a chunk
  bx = (lin / NY) % NX;
  z  = lin / (NY * NX);
}

#define READ_A8(BUF, HALF)                                                  \
  _Pragma("unroll")                                                         \
  for (int ks = 0; ks < 2; ++ks)                                            \
    _Pragma("unroll")                                                       \
    for (int mi = 0; mi < 4; ++mi)                                          \
      a[ks * 4 + mi] =                                                      \
          frag256(&L[BUF][0][HALF][0], wr + mi * 16 + lr, ks * 64 + q16);

#define READ_B4(BREG, BUF, HALF)                                            \
  _Pragma("unroll")                                                         \
  for (int ks = 0; ks < 2; ++ks)                                            \
    _Pragma("unroll")                                                       \
    for (int ni = 0; ni < 2; ++ni)                                          \
      BREG[ks * 2 + ni] =                                                   \
          frag256(&L[BUF][1][HALF][0], wc + ni * 16 + lr, ks * 64 + q16);

#define MMA_QUAD(MOFF, NOFF, BREG)                                          \
  __builtin_amdgcn_s_setprio(1);                                            \
  _Pragma("unroll")                                                         \
  for (int ks = 0; ks < 2; ++ks)                                            \
    _Pragma("unroll")                                                       \
    for (int mi = 0; mi < 4; ++mi)                                          \
      _Pragma("unroll")                                                     \
      for (int ni = 0; ni < 2; ++ni)                                        \
        acc[(MOFF) + mi][(NOFF) + ni] =                                     \
            __builtin_amdgcn_mfma_f32_16x16x32_bf16(                        \
                a[ks * 4 + mi], BREG[ks * 2 + ni],                          \
                acc[(MOFF) + mi][(NOFF) + ni], 0, 0, 0);                    \
  __builtin_amdgcn_s_setprio(0);

// ==================== 256x256 4-phase core (R6, proven) ======================
// C[M,N] = A[M,K]·B[N,K]^T * scale + bias; mode 0 = bf16 store, 2 = f32.
__global__ __launch_bounds__(512, 2) void gemm256_bt(
    const __hip_bfloat16* __restrict__ A,
    const __hip_bfloat16* __restrict__ B,
    void* __restrict__ Cv,
    const float* __restrict__ bias,
    int K, int ldA, int ldB, int ldC,
    long sA_, long sB_, long sC_,
    float scale, int mode)
{
  __shared__ __hip_bfloat16 L[2][2][2][128 * 64];   // [buf][mat][half]

  const int tid  = threadIdx.x;
  const int lane = tid & 63;
  const int wid  = tid >> 6;
  const int wr   = (wid >> 2) * 64;
  const int wc   = (wid & 3) * 32;
  const int lr   = lane & 15;
  const int q    = lane >> 4;
  const int q16  = q * 16;

  int bx, by; long z;
  xcd_decode(gridDim.x, gridDim.y, gridDim.z, bx, by, z);

  const long rowBase = (long)bx * 256;
  const long colBase = (long)by * 256;
  const __hip_bfloat16* Ab = A + z * sA_;
  const __hip_bfloat16* Bb = B + z * sB_;

  f32x4 acc[8][4] = {};
  bf16x8 a[8], bA[4], bB[4];
  const int KT = K >> 6;

  // ---- prologue: 6 stages (12 loads), publish A0[0],B0[0] ----
  {
    const int kk1 = (KT > 1 ? 1 : 0) * 64;
    stage_half(Ab, &L[0][0][0][0], rowBase,       ldA, 0,   tid);  // A0[0]
    stage_half(Bb, &L[0][1][0][0], colBase,       ldB, 0,   tid);  // B0[0]
    stage_half(Bb, &L[0][1][1][0], colBase + 128, ldB, 0,   tid);  // B1[0]
    stage_half(Ab, &L[0][0][1][0], rowBase + 128, ldA, 0,   tid);  // A1[0]
    stage_half(Ab, &L[1][0][0][0], rowBase,       ldA, kk1, tid);  // A0[1]
    stage_half(Bb, &L[1][1][0][0], colBase,       ldB, kk1, tid);  // B0[1]
    WAITV(8);   // retire A0[0], B0[0]
    BAR;
  }

  for (int kt = 0; kt < KT; ++kt) {
    const int cur = kt & 1, nxt = cur ^ 1;
    const int t1 = kt + 1 < KT ? kt + 1 : KT - 1;
    const int t2 = kt + 2 < KT ? kt + 2 : KT - 1;
    const int k1 = t1 << 6, k2 = t2 << 6;

    // ---- p0 ----
    stage_half(Bb, &L[nxt][1][1][0], colBase + 128, ldB, k1, tid);  // B1[t+1]
    WAITV(8);
    READ_A8(cur, 0);
    READ_B4(bA, cur, 0);
    BAR;
    MMA_QUAD(0, 0, bA);
    // ---- p1 ----
    stage_half(Ab, &L[nxt][0][1][0], rowBase + 128, ldA, k1, tid);  // A1[t+1]
    WAITV(8);
    READ_B4(bB, cur, 1);
    BAR;
    MMA_QUAD(0, 2, bB);
    // ---- p2 ----
    stage_half(Ab, &L[cur][0][0][0], rowBase, ldA, k2, tid);        // A0[t+2]
    WAITV(8);
    READ_A8(cur, 1);
    BAR;
    MMA_QUAD(4, 2, bB);
    // ---- p3 ----
    stage_half(Bb, &L[cur][1][0][0], colBase, ldB, k2, tid);        // B0[t+2]
    WAITV(8);
    BAR;
    MMA_QUAD(4, 0, bA);
  }
  WAITV(0);   // drain redundant tail stages

  // ---- epilogue ----
  const long cz = z * sC_;
  #pragma unroll
  for (int n = 0; n < 4; ++n) {
    long col = colBase + (n >> 1) * 128 + wc + (n & 1) * 16 + lr;
    float bv = bias ? bias[col] : 0.0f;
    #pragma unroll
    for (int m = 0; m < 8; ++m) {
      long row0 = rowBase + (m >> 2) * 128 + wr + (m & 3) * 16 + q * 4;
      f32x4 v = acc[m][n];
      #pragma unroll
      for (int i = 0; i < 4; ++i) {
        float val = v[i] * scale + bv;
        if (mode == 0)
          ((__hip_bfloat16*)Cv)[cz + (row0 + i) * (long)ldC + col] =
              __float2bfloat16(val);
        else
          ((float*)Cv)[cz + (row0 + i) * (long)ldC + col] = val;
      }
    }
  }
}

// ==================== 128x256 2-phase triple-buffered core (R6, proven) ======
__global__ __launch_bounds__(512, 2) void gemm128_bt(
    const __hip_bfloat16* __restrict__ A,
    const __hip_bfloat16* __restrict__ B,
    void* __restrict__ Cv,
    const float* __restrict__ bias,
    int K, int ldA, int ldB, int ldC,
    long sA_, long sB_, long sC_,
    float scale, int mode)
{
  __shared__ __hip_bfloat16 L[3][3][128 * 64];   // [buf][region]

  const int tid  = threadIdx.x;
  const int lane = tid & 63;
  const int wid  = tid >> 6;
  const int wr   = (wid >> 2) * 64;
  const int wc   = (wid & 3) * 32;
  const int lr   = lane & 15;
  const int q    = lane >> 4;
  const int q16  = q * 16;

  int bx, by; long z;
  xcd_decode(gridDim.x, gridDim.y, gridDim.z, bx, by, z);

  const long rowBase = (long)bx * 128;
  const long colBase = (long)by * 256;
  const __hip_bfloat16* Ab = A + z * sA_;
  const __hip_bfloat16* Bb = B + z * sB_;

  f32x4 acc[4][4] = {};
  bf16x8 a[8], bA[4], bB[4];
  const int KT = K >> 6;

  // ---- prologue: tiles 0,1 (12 loads); publish A[0],B0[0] ----
  {
    const int kk1 = (KT > 1 ? 1 : 0) * 64;
    stage_half(Ab, &L[0][0][0], rowBase,       ldA, 0,   tid);  // A[0]
    stage_half(Bb, &L[0][1][0], colBase,       ldB, 0,   tid);  // B0[0]
    stage_half(Bb, &L[0][2][0], colBase + 128, ldB, 0,   tid);  // B1[0]
    stage_half(Ab, &L[1][0][0], rowBase,       ldA, kk1, tid);  // A[1]
    stage_half(Bb, &L[1][1][0], colBase,       ldB, kk1, tid);  // B0[1]
    stage_half(Bb, &L[1][2][0], colBase + 128, ldB, kk1, tid);  // B1[1]
    WAITV(8);   // retire A[0],B0[0]
    BAR;
  }

  int cur = 0, nx2 = 2;
  for (int t = 0; t < KT; ++t) {
    const int kc = ((t + 2 < KT) ? (t + 2) : (KT - 1)) << 6;
    // ---- ph0 ----
    stage_half(Ab, &L[nx2][0][0], rowBase,       ldA, kc, tid);  // A[t+2]
    stage_half(Bb, &L[nx2][1][0], colBase,       ldB, kc, tid);  // B0[t+2]
    WAITV(10);                                   // publish B1[t]
    #pragma unroll
    for (int ks = 0; ks < 2; ++ks)
      #pragma unroll
      for (int mi = 0; mi < 4; ++mi)
        a[ks * 4 + mi] = frag256(&L[cur][0][0], wr + mi * 16 + lr, ks * 64 + q16);
    #pragma unroll
    for (int ks = 0; ks < 2; ++ks)
      #pragma unroll
      for (int ni = 0; ni < 2; ++ni)
        bA[ks * 2 + ni] = frag256(&L[cur][1][0], wc + ni * 16 + lr, ks * 64 + q16);
    BAR;
    __builtin_amdgcn_s_setprio(1);
    #pragma unroll
    for (int ks = 0; ks < 2; ++ks)
      #pragma unroll
      for (int mi = 0; mi < 4; ++mi)
        #pragma unroll
        for (int ni = 0; ni < 2; ++ni)
          acc[mi][ni] = __builtin_amdgcn_mfma_f32_16x16x32_bf16(
              a[ks * 4 + mi], bA[ks * 2 + ni], acc[mi][ni], 0, 0, 0);
    __builtin_amdgcn_s_setprio(0);
    // ---- ph1 ----
    stage_half(Bb, &L[nx2][2][0], colBase + 128, ldB, kc, tid);  // B1[t+2]
    WAITV(8);                                    // publish A[t+1],B0[t+1]
    #pragma unroll
    for (int ks = 0; ks < 2; ++ks)
      #pragma unroll
      for (int ni = 0; ni < 2; ++ni)
        bB[ks * 2 + ni] = frag256(&L[cur][2][0], wc + ni * 16 + lr, ks * 64 + q16);
    BAR;
    __builtin_amdgcn_s_setprio(1);
    #pragma unroll
    for (int ks = 0; ks < 2; ++ks)
      #pragma unroll
      for (int mi = 0; mi < 4; ++mi)
        #pragma unroll
        for (int ni = 0; ni < 2; ++ni)
          acc[mi][2 + ni] = __builtin_amdgcn_mfma_f32_16x16x32_bf16(
              a[ks * 4 + mi], bB[ks * 2 + ni], acc[mi][2 + ni], 0, 0, 0);
    __builtin_amdgcn_s_setprio(0);
    cur = (cur == 2) ? 0 : cur + 1;
    nx2 = (nx2 == 2) ? 0 : nx2 + 1;
  }
  WAITV(0);

  // ---- epilogue ----
  const long cz = z * sC_;
  #pragma unroll
  for (int n = 0; n < 4; ++n) {
    long col = colBase + (n >> 1) * 128 + wc + (n & 1) * 16 + lr;
    float bv = bias ? bias[col] : 0.0f;
    #pragma unroll
    for (int m = 0; m < 4; ++m) {
      long row0 = rowBase + wr + m * 16 + q * 4;
      f32x4 v = acc[m][n];
      #pragma unroll
      for (int i = 0; i < 4; ++i) {
        float val = v[i] * scale + bv;
        if (mode == 0)
          ((__hip_bfloat16*)Cv)[cz + (row0 + i) * (long)ldC + col] =
              __float2bfloat16(val);
        else
          ((float*)Cv)[cz + (row0 + i) * (long)ldC + col] = val;
      }
    }
  }
}

// ==================== small helpers ==========================================
__global__ __launch_bounds__(256) void cvt_f32_bf16(
    const float* __restrict__ in, __hip_bfloat16* __restrict__ out)
{
  long i = ((long)blockIdx.x * 256 + threadIdx.x) * 8;
  float4 a = *(const float4*)(in + i);
  float4 b = *(const float4*)(in + i + 4);
  bf16x8 o;
  o[0] = __builtin_bit_cast(short, __float2bfloat16(a.x));
  o[1] = __builtin_bit_cast(short, __float2bfloat16(a.y));
  o[2] = __builtin_bit_cast(short, __float2bfloat16(a.z));
  o[3] = __builtin_bit_cast(short, __float2bfloat16(a.w));
  o[4] = __builtin_bit_cast(short, __float2bfloat16(b.x));
  o[5] = __builtin_bit_cast(short, __float2bfloat16(b.y));
  o[6] = __builtin_bit_cast(short, __float2bfloat16(b.z));
  o[7] = __builtin_bit_cast(short, __float2bfloat16(b.w));
  *(bf16x8*)(out + i) = o;
}

// Merged straight converts: Wq, Wk, Wo (512 blocks each).
__global__ __launch_bounds__(256) void cvt_w3_f32_bf16(
    const float* __restrict__ Wq, const float* __restrict__ Wk,
    const float* __restrict__ Wo,
    __hip_bfloat16* __restrict__ oQ, __hip_bfloat16* __restrict__ oK,
    __hip_bfloat16* __restrict__ oO)
{
  int blk = blockIdx.x;
  const float* in; __hip_bfloat16* out;
  if (blk < 512)        { in = Wq; out = oQ; }
  else if (blk < 1024)  { in = Wk; out = oK; blk -= 512; }
  else                  { in = Wo; out = oO; blk -= 1024; }
  long i = ((long)blk * 256 + threadIdx.x) * 8;
  float4 a = *(const float4*)(in + i);
  float4 b = *(const float4*)(in + i + 4);
  bf16x8 o;
  o[0] = __builtin_bit_cast(short, __float2bfloat16(a.x));
  o[1] = __builtin_bit_cast(short, __float2bfloat16(a.y));
  o[2] = __builtin_bit_cast(short, __float2bfloat16(a.z));
  o[3] = __builtin_bit_cast(short, __float2bfloat16(a.w));
  o[4] = __builtin_bit_cast(short, __float2bfloat16(b.x));
  o[5] = __builtin_bit_cast(short, __float2bfloat16(b.y));
  o[6] = __builtin_bit_cast(short, __float2bfloat16(b.z));
  o[7] = __builtin_bit_cast(short, __float2bfloat16(b.w));
  *(bf16x8*)(out + i) = o;
}

__global__ __launch_bounds__(256) void cvt_t_f32_bf16(
    const float* __restrict__ in, __hip_bfloat16* __restrict__ out)
{
  __shared__ __hip_bfloat16 t[64][65];
  const int tid = threadIdx.x;
  const long rb = (long)blockIdx.y * 64;
  const long cb = (long)blockIdx.x * 64;
  const int r0 = tid >> 4;
  const int c0 = (tid & 15) * 4;
  #pragma unroll
  for (int p = 0; p < 4; ++p) {
    int r = r0 + p * 16;
    float4 v = *(const float4*)(in + (rb + r) * 1024 + cb + c0);
    t[c0 + 0][r] = __float2bfloat16(v.x);
    t[c0 + 1][r] = __float2bfloat16(v.y);
    t[c0 + 2][r] = __float2bfloat16(v.z);
    t[c0 + 3][r] = __float2bfloat16(v.w);
  }
  __syncthreads();
  #pragma unroll
  for (int p = 0; p < 4; ++p) {
    int r = r0 + p * 16;
    __hip_bfloat16* o = out + (cb + r) * 1024 + rb + c0;
    o[0] = t[r][c0 + 0]; o[1] = t[r][c0 + 1];
    o[2] = t[r][c0 + 2]; o[3] = t[r][c0 + 3];
  }
}

// Wvo partial reduce: Wvo_bf16 = sum of 4 f32 partials (K-split).
__global__ __launch_bounds__(256) void reduce_wvo(
    const float* __restrict__ p, __hip_bfloat16* __restrict__ out)
{
  const long S1 = 1024L * 1024L;
  long i = ((long)blockIdx.x * 256 + threadIdx.x) * 4;
  float4 a = *(const float4*)(p + i);
  float4 b = *(const float4*)(p + i + S1);
  float4 c = *(const float4*)(p + i + 2 * S1);
  float4 d = *(const float4*)(p + i + 3 * S1);
  bf16x4 o;
  o[0] = __builtin_bit_cast(short, __float2bfloat16(a.x + b.x + c.x + d.x));
  o[1] = __builtin_bit_cast(short, __float2bfloat16(a.y + b.y + c.y + d.y));
  o[2] = __builtin_bit_cast(short, __float2bfloat16(a.z + b.z + c.z + d.z));
  o[3] = __builtin_bit_cast(short, __float2bfloat16(a.w + b.w + c.w + d.w));
  *(bf16x4*)(out + i) = o;
}

// Fused: blocks 0..255 -> bfinal = Wo·bv + bo ; blocks 256..263 -> bqk = bq|bk.
__global__ __launch_bounds__(256) void bias_fuse(
    const float* __restrict__ Wo, const float* __restrict__ bv,
    const float* __restrict__ bo, const float* __restrict__ bq,
    const float* __restrict__ bk, float* __restrict__ bfinal,
    float* __restrict__ bqk)
{
  int blk = blockIdx.x;
  if (blk < 256) {
    int e = blk * 4 + (threadIdx.x >> 6);
    int lane = threadIdx.x & 63;
    const float* row = Wo + (long)e * 1024;
    float s = 0.0f;
    #pragma unroll
    for (int p = 0; p < 4; ++p) {
      float4 w = *(const float4*)(row + p * 256 + lane * 4);
      float4 b = *(const float4*)(bv + p * 256 + lane * 4);
      s += w.x * b.x + w.y * b.y + w.z * b.z + w.w * b.w;
    }
    #pragma unroll
    for (int o = 32; o; o >>= 1) s += __shfl_xor(s, o);
    if (lane == 0) bfinal[e] = s + bo[e];
  } else {
    int i = (blk - 256) * 256 + threadIdx.x;
    bqk[i] = (i < 1024) ? bq[i] : bk[i - 1024];
  }
}

__global__ __launch_bounds__(256) void softmax_rows(__hip_bfloat16* __restrict__ P)
{
  const int tid  = threadIdx.x;
  const int lane = tid & 63;
  const int wid  = tid >> 6;
  __hip_bfloat16* p = P + (long)blockIdx.x * 2048 + tid * 8;

  bf16x8 v = *(const bf16x8*)p;
  float x[8];
  #pragma unroll
  for (int i = 0; i < 8; ++i)
    x[i] = __uint_as_float(((unsigned)(unsigned short)v[i]) << 16);

  float m = x[0];
  #pragma unroll
  for (int i = 1; i < 8; ++i) m = fmaxf(m, x[i]);
  #pragma unroll
  for (int o = 32; o; o >>= 1) m = fmaxf(m, __shfl_xor(m, o));

  __shared__ float rmax[4], rsum[4];
  if (lane == 0) rmax[wid] = m;
  __syncthreads();
  m = fmaxf(fmaxf(rmax[0], rmax[1]), fmaxf(rmax[2], rmax[3]));

  float e[8], s = 0.0f;
  #pragma unroll
  for (int i = 0; i < 8; ++i) { e[i] = __expf(x[i] - m); s += e[i]; }
  #pragma unroll
  for (int o = 32; o; o >>= 1) s += __shfl_xor(s, o);
  if (lane == 0) rsum[wid] = s;
  __syncthreads();
  s = (rsum[0] + rsum[1]) + (rsum[2] + rsum[3]);

  float inv = 1.0f / s;
  bf16x8 ov;
  #pragma unroll
  for (int i = 0; i < 8; ++i) {
    __hip_bfloat16 h = __float2bfloat16(e[i] * inv);
    ov[i] = __builtin_bit_cast(short, h);
  }
  *(bf16x8*)p = ov;
}

extern "C" void kernel_launch(void* const* d_in, const int* in_sizes, int n_in,
                              void* d_out, int out_size, void* d_ws, size_t ws_size,
                              hipStream_t stream) {
  const float* x  = (const float*)d_in[0];
  const float* Wq = (const float*)d_in[1];
  const float* bq = (const float*)d_in[2];
  const float* Wk = (const float*)d_in[3];
  const float* bk = (const float*)d_in[4];
  const float* Wv = (const float*)d_in[5];
  const float* bv = (const float*)d_in[6];
  const float* Wo = (const float*)d_in[7];
  const float* bo = (const float*)d_in[8];
  float* out = (float*)d_out;

  const long B = 4, S = 2048, D = 1024;
  char* ws = (char*)d_ws;
  __hip_bfloat16* xb   = (__hip_bfloat16*)ws; ws += B * S * D * 2;     // 16 MiB
  __hip_bfloat16* Wqkb = (__hip_bfloat16*)ws; ws += 2 * D * D * 2;     //  4 MiB (Wq|Wk rows)
  __hip_bfloat16* Wob  = (__hip_bfloat16*)ws; ws += D * D * 2;         //  2 MiB
  __hip_bfloat16* QK   = (__hip_bfloat16*)ws; ws += (B * S) * (2 * D) * 2; // 32 MiB [8192][2048]
  __hip_bfloat16* VWot = (__hip_bfloat16*)ws; ws += B * D * S * 2;     // 16 MiB [B][D][S]
  __hip_bfloat16* P    = (__hip_bfloat16*)ws; ws += B * S * S * 2;     // 32 MiB
  // Aliases (dead-region reuse):
  __hip_bfloat16* Wvtb   = QK;                     // Wv^T bf16 (2 MiB), dead before QK write
  float*          Wvop   = (float*)(QK + 2 * D * D); // 4 x 4MiB f32 partials in QK region
  __hip_bfloat16* Wvo    = P;                      // Wvo bf16, dead before P write
  float*          bfinal = (float*)Wob;            // after Wvo GEMM reads Wob
  float*          bqk    = (float*)Wob + 1024;     // concat(bq,bk), same region

  dim3 blk(256);
  dim3 blk5(512);
  // converts
  cvt_f32_bf16<<<dim3(4096), blk, 0, stream>>>(x, xb);
  cvt_w3_f32_bf16<<<dim3(1536), blk, 0, stream>>>(Wq, Wk, Wo,
                                                  Wqkb, Wqkb + D * D, Wob);
  cvt_t_f32_bf16<<<dim3(16, 16), blk, 0, stream>>>(Wv, Wvtb);

  // Wvo = Wo·Wv, K-split z=4x256 on gemm128 (z-strides = K-offsets), f32 partials
  gemm128_bt<<<dim3(8, 4, 4), blk5, 0, stream>>>(
      Wob, Wvtb, Wvop, nullptr, 256, 1024, 1024, 1024,
      256, 256, 1024L * 1024L, 1.0f, 2);
  reduce_wvo<<<dim3(1024), blk, 0, stream>>>(Wvop, Wvo);
  // bfinal = Wo·bv + bo ; bqk = bq|bk  (overwrites Wob region — after Wvo GEMM)
  bias_fuse<<<dim3(264), blk, 0, stream>>>(Wo, bv, bo, bq, bk, bfinal, bqk);

  // QK = xb · Wqkb^T + (bq|bk):  M=8192, N=2048, K=1024  -> [8192][2048]
  gemm256_bt<<<dim3(32, 8, 1), blk5, 0, stream>>>(
      xb, Wqkb, QK, bqk, 1024, 1024, 1024, 2048, 0, 0, 0, 1.0f, 0);
  // VWo^T = Wvo · xb^T (batched): M=1024, N=2048, K=1024 -> [B][D][S]
  gemm128_bt<<<dim3(8, 8, 4), blk5, 0, stream>>>(
      Wvo, xb, VWot, nullptr, 1024, 1024, 1024, 2048, 0, S * D, D * S, 1.0f, 0);
  // scores: P = Q·K^T * 0.125 (batched): M=N=2048, K=1024
  gemm256_bt<<<dim3(8, 8, 4), blk5, 0, stream>>>(
      QK, QK + 1024, P, nullptr, 1024, 2048, 2048, 2048,
      S * 2048, S * 2048, S * S, 0.125f, 0);
  // softmax over each of 4*2048 rows
  softmax_rows<<<dim3(8192), blk, 0, stream>>>(P);
  // out = P · VWot^T + bfinal (f32): M=2048, N=1024, K=2048 (batched)
  gemm128_bt<<<dim3(16, 4, 4), blk5, 0, stream>>>(
      P, VWot, out, bfinal, 2048, 2048, 2048, 1024,
      S * S, D * S, S * D, 1.0f, 2);
}